// Round 4
// baseline (113.953 us; speedup 1.0000x reference)
//
#include <hip/hip_runtime.h>

// Problem constants (from reference):
//   depth: [B, D, H, W] fp32,  grid: [B, NN*H, W, 2] fp32 in [-1,1]
//   out  : [B, D+NN, H, W] fp32, sorted ascending along channel axis
constexpr int B  = 4;
constexpr int D  = 8;
constexpr int H  = 512;
constexpr int W  = 640;
constexpr int NN = 9;
constexpr int HW  = H * W;
constexpr int HW2 = HW / 2;
constexpr int W2  = W / 2;
constexpr int NC = D + NN;  // 17

// 8-byte pair with 4-byte alignment: compiler emits global_load_dwordx2
// (gfx950 handles 4B-aligned 8B loads) for the [x0, x0+1] pair.
struct __attribute__((packed, aligned(4))) fpair { float a, b; };

// Bilinear sample of `center` at normalized (gx, gy), border padding,
// align_corners=false — exact replica of the reference arithmetic.
__device__ __forceinline__ float bsample(const float* __restrict__ center,
                                         float gx, float gy) {
  float ix = ((gx + 1.0f) * (float)W - 1.0f) * 0.5f;
  float iy = ((gy + 1.0f) * (float)H - 1.0f) * 0.5f;
  ix = fminf(fmaxf(ix, 0.0f), (float)(W - 1));
  iy = fminf(fmaxf(iy, 0.0f), (float)(H - 1));

  float x0f = floorf(ix);
  float y0f = floorf(iy);
  float wx = ix - x0f;
  float wy = iy - y0f;

  int x0 = (int)x0f;
  int y0 = (int)y0f;
  int y1 = min(y0 + 1, H - 1);

  // When wx == 0 the .b element has weight 0; wx > 0 implies x0 <= W-2,
  // so the 8B pair read is either exact or harmlessly zero-weighted
  // (and always inside the depth allocation: center is plane 4 of 8).
  fpair p0 = *reinterpret_cast<const fpair*>(center + y0 * W + x0);
  fpair p1 = *reinterpret_cast<const fpair*>(center + y1 * W + x0);

  float vtop = p0.a * (1.0f - wx) + p0.b * wx;
  float vbot = p1.a * (1.0f - wx) + p1.b * wx;
  return vtop * (1.0f - wy) + vbot * wy;
}

__device__ __forceinline__ void sort17(float* v) {
  // Branch-free odd-even transposition network, fully unrolled,
  // compile-time indices only (stays in registers).
#pragma unroll
  for (int pass = 0; pass < NC; ++pass) {
#pragma unroll
    for (int i = (pass & 1); i + 1 < NC; i += 2) {
      float lo = fminf(v[i], v[i + 1]);
      float hi = fmaxf(v[i], v[i + 1]);
      v[i] = lo;
      v[i + 1] = hi;
    }
  }
}

// Two horizontally-adjacent pixels per thread: two independent dependency
// chains per wave (2x memory-level parallelism) and 2x fewer coalesced
// load/store instructions per pixel (float4 grid, float2 depth/out).
__global__ __launch_bounds__(256) void prop_sort_kernel(
    const float* __restrict__ depth,
    const float* __restrict__ grid,
    float* __restrict__ out) {
  int idx = blockIdx.x * blockDim.x + threadIdx.x;
  if (idx >= B * HW2) return;

  int b  = idx / HW2;
  int r  = idx - b * HW2;
  int h  = r / W2;
  int w2 = r - h * W2;
  int w  = w2 * 2;
  int hw = h * W + w;

  float va[NC], vb[NC];

  // ---- 8 depth channels for both pixels (coalesced float2) ----
  const float* dptr = depth + (size_t)b * D * HW + hw;
#pragma unroll
  for (int d = 0; d < D; ++d) {
    float2 t = *reinterpret_cast<const float2*>(dptr + (size_t)d * HW);
    va[d] = t.x;
    vb[d] = t.y;
  }

  // ---- bilinear grid_sample of the center plane for both pixels ----
  const float* center = depth + (size_t)b * D * HW + (size_t)(D / 2) * HW;
  // grid viewed as float4 [B, NN*H, W/2]: one load covers both pixels' (x,y)
  const float4* gp = reinterpret_cast<const float4*>(grid)
                     + ((size_t)b * NN * H + h) * W2 + w2;

#pragma unroll
  for (int n = 0; n < NN; ++n) {
    float4 g = gp[(size_t)n * HW2];
    va[D + n] = bsample(center, g.x, g.y);
    vb[D + n] = bsample(center, g.z, g.w);
  }

  // ---- sort both pixels' 17 values ----
  sort17(va);
  sort17(vb);

  // ---- write 17 output planes (coalesced float2) ----
  float* optr = out + (size_t)b * NC * HW + hw;
#pragma unroll
  for (int c = 0; c < NC; ++c) {
    *reinterpret_cast<float2*>(optr + (size_t)c * HW) = make_float2(va[c], vb[c]);
  }
}

extern "C" void kernel_launch(void* const* d_in, const int* in_sizes, int n_in,
                              void* d_out, int out_size, void* d_ws, size_t ws_size,
                              hipStream_t stream) {
  const float* depth = (const float*)d_in[0];
  const float* grid  = (const float*)d_in[1];
  float* out = (float*)d_out;

  int total = B * HW2;          // 655,360 threads (two pixels per thread)
  int block = 256;
  int nblocks = (total + block - 1) / block;  // 2560
  prop_sort_kernel<<<nblocks, block, 0, stream>>>(depth, grid, out);
}

// Round 5
// 113.626 us; speedup vs baseline: 1.0029x; 1.0029x over previous
//
#include <hip/hip_runtime.h>

// Problem constants (from reference):
//   depth: [B, D, H, W] fp32,  grid: [B, NN*H, W, 2] fp32 in [-1,1]
//   out  : [B, D+NN, H, W] fp32, sorted ascending along channel axis
constexpr int B  = 4;
constexpr int D  = 8;
constexpr int H  = 512;
constexpr int W  = 640;
constexpr int NN = 9;
constexpr int HW = H * W;
constexpr int NC = D + NN;  // 17
constexpr int BLOCK = 256;
constexpr int BLOCKS_PER_B = HW / BLOCK;  // 1280 (HW % 256 == 0 -> b uniform per block)

__device__ __forceinline__ void sort17(float* v) {
  // Branch-free odd-even transposition network, fully unrolled,
  // compile-time indices only (stays in registers).
#pragma unroll
  for (int pass = 0; pass < NC; ++pass) {
#pragma unroll
    for (int i = (pass & 1); i + 1 < NC; i += 2) {
      float lo = fminf(v[i], v[i + 1]);
      float hi = fmaxf(v[i], v[i + 1]);
      v[i] = lo;
      v[i + 1] = hi;
    }
  }
}

__global__ __launch_bounds__(256) void prop_sort_kernel(
    const float* __restrict__ depth,
    const float* __restrict__ grid,
    float* __restrict__ out) {
  // b derived from blockIdx only -> stays in SGPR; center base is wave-uniform.
  int b  = blockIdx.x / BLOCKS_PER_B;
  int hw = (blockIdx.x - b * BLOCKS_PER_B) * BLOCK + threadIdx.x;
  int h  = hw / W;
  int w  = hw - h * W;

  const float* center = depth + (size_t)b * D * HW + (size_t)(D / 2) * HW;

  // ---- load all 9 grid float2 (coalesced, stride H*W) ----
  const float2* gp = reinterpret_cast<const float2*>(grid)
                     + ((size_t)b * NN * H + h) * W + w;
  float2 g[NN];
#pragma unroll
  for (int n = 0; n < NN; ++n) g[n] = gp[(size_t)n * HW];

  // ---- compute offsets and ISSUE all 18 pair-gathers via inline asm ----
  // asm volatile forces the loads to be issued back-to-back (compiler cannot
  // serialize them the way it did with plain loads in R2/R4). saddr form:
  // 32-bit byte voffset + SGPR base (block-uniform).
  float wx[NN], wy[NN];
  float2 r0[NN], r1[NN];
#pragma unroll
  for (int n = 0; n < NN; ++n) {
    float ix = ((g[n].x + 1.0f) * (float)W - 1.0f) * 0.5f;
    float iy = ((g[n].y + 1.0f) * (float)H - 1.0f) * 0.5f;
    ix = fminf(fmaxf(ix, 0.0f), (float)(W - 1));
    iy = fminf(fmaxf(iy, 0.0f), (float)(H - 1));

    float x0f = floorf(ix);
    float y0f = floorf(iy);
    wx[n] = ix - x0f;
    wy[n] = iy - y0f;

    int x0 = (int)x0f;
    int y0 = (int)y0f;
    int y1 = min(y0 + 1, H - 1);

    // Pair [x0, x0+1]: when wx==0 the second lane has weight 0, and wx>0
    // implies x0 <= W-2, so the 8B read is exact or harmlessly 0-weighted;
    // always inside the depth allocation (center is plane 4 of 8).
    unsigned off0 = (unsigned)((y0 * W + x0) * 4);
    unsigned off1 = (unsigned)((y1 * W + x0) * 4);
    asm volatile("global_load_dwordx2 %0, %1, %2"
                 : "=v"(r0[n]) : "v"(off0), "s"(center));
    asm volatile("global_load_dwordx2 %0, %1, %2"
                 : "=v"(r1[n]) : "v"(off1), "s"(center));
  }

  // ---- depth-channel loads (coalesced) — issued while gathers in flight ----
  const float* dptr = depth + (size_t)b * D * HW + hw;
  float vdep[D];
#pragma unroll
  for (int d = 0; d < D; ++d) vdep[d] = dptr[(size_t)d * HW];

  // Drain everything, then fence the scheduler so register-only consumers
  // cannot be hoisted above the wait (guide rule #18).
  asm volatile("s_waitcnt vmcnt(0)" ::: "memory");
  __builtin_amdgcn_sched_barrier(0);

  // ---- bilinear combine + sort + write ----
  float v[NC];
#pragma unroll
  for (int d = 0; d < D; ++d) v[d] = vdep[d];
#pragma unroll
  for (int n = 0; n < NN; ++n) {
    float vtop = r0[n].x * (1.0f - wx[n]) + r0[n].y * wx[n];
    float vbot = r1[n].x * (1.0f - wx[n]) + r1[n].y * wx[n];
    v[D + n] = vtop * (1.0f - wy[n]) + vbot * wy[n];
  }

  sort17(v);

  float* optr = out + (size_t)b * NC * HW + hw;
#pragma unroll
  for (int c = 0; c < NC; ++c) {
    optr[(size_t)c * HW] = v[c];
  }
}

extern "C" void kernel_launch(void* const* d_in, const int* in_sizes, int n_in,
                              void* d_out, int out_size, void* d_ws, size_t ws_size,
                              hipStream_t stream) {
  const float* depth = (const float*)d_in[0];
  const float* grid  = (const float*)d_in[1];
  float* out = (float*)d_out;

  int nblocks = B * BLOCKS_PER_B;  // 5120, exact (no tail guard needed)
  prop_sort_kernel<<<nblocks, BLOCK, 0, stream>>>(depth, grid, out);
}

// Round 6
// 89.574 us; speedup vs baseline: 1.2722x; 1.2685x over previous
//
#include <hip/hip_runtime.h>

// Problem constants (from reference):
//   depth: [B, D, H, W] fp32,  grid: [B, NN*H, W, 2] fp32 in [-1,1]
//   out  : [B, D+NN, H, W] fp32, sorted ascending along channel axis
constexpr int B  = 4;
constexpr int D  = 8;
constexpr int H  = 512;
constexpr int W  = 640;
constexpr int NN = 9;
constexpr int HW = H * W;
constexpr int NC = D + NN;  // 17
constexpr int BLOCK = 256;
constexpr int BLOCKS_PER_B = HW / BLOCK;  // 1280 (HW % 256 == 0 -> b uniform per block)

// Row-pair table: T[b][y][x] = (center[y][x], center[min(y+1,H-1)][x]),
// width padded to W+1 (x == W duplicates x == W-1) so the dwordx4 gather
// at (y0, x0) is always in-bounds for x0 <= W-1.
constexpr int WP = W + 1;
constexpr int TPLANE = H * WP;                       // float2 elements per batch
constexpr size_t T_BYTES = (size_t)B * TPLANE * 8;   // 10,502,144 bytes

__global__ __launch_bounds__(256) void build_T_kernel(
    const float* __restrict__ depth, float2* __restrict__ T) {
  int idx = blockIdx.x * blockDim.x + threadIdx.x;
  if (idx >= B * TPLANE) return;
  int b = idx / TPLANE;
  int r = idx - b * TPLANE;
  int y = r / WP;
  int x = r - y * WP;
  int xs = min(x, W - 1);
  int y1 = min(y + 1, H - 1);
  const float* c = depth + (size_t)b * D * HW + (size_t)(D / 2) * HW;
  T[idx] = make_float2(c[y * W + xs], c[y1 * W + xs]);
}

__device__ __forceinline__ void sort17(float* v) {
  // Branch-free odd-even transposition network, fully unrolled,
  // compile-time indices only (stays in registers).
#pragma unroll
  for (int pass = 0; pass < NC; ++pass) {
#pragma unroll
    for (int i = (pass & 1); i + 1 < NC; i += 2) {
      float lo = fminf(v[i], v[i + 1]);
      float hi = fmaxf(v[i], v[i + 1]);
      v[i] = lo;
      v[i + 1] = hi;
    }
  }
}

// Main kernel using the row-pair table: ONE dwordx4 gather per neighbor
// (4 bilinear corners in one line request) instead of two dwordx2.
__global__ __launch_bounds__(256) void prop_sort_T_kernel(
    const float* __restrict__ depth,
    const float* __restrict__ grid,
    const float2* __restrict__ T,
    float* __restrict__ out) {
  int b  = blockIdx.x / BLOCKS_PER_B;          // SGPR (blockIdx only)
  int hw = (blockIdx.x - b * BLOCKS_PER_B) * BLOCK + threadIdx.x;
  int h  = hw / W;
  int w  = hw - h * W;

  const float2* Tb = T + (size_t)b * TPLANE;   // wave-uniform base -> SGPR

  // ---- load all 9 grid float2 (coalesced, stride H*W) ----
  const float2* gp = reinterpret_cast<const float2*>(grid)
                     + ((size_t)b * NN * H + h) * W + w;
  float2 g[NN];
#pragma unroll
  for (int n = 0; n < NN; ++n) g[n] = gp[(size_t)n * HW];

  // ---- compute offsets, ISSUE all 9 dwordx4 gathers (batched via asm) ----
  float wx[NN], wy[NN];
  float4 q[NN];
#pragma unroll
  for (int n = 0; n < NN; ++n) {
    float ix = ((g[n].x + 1.0f) * (float)W - 1.0f) * 0.5f;
    float iy = ((g[n].y + 1.0f) * (float)H - 1.0f) * 0.5f;
    ix = fminf(fmaxf(ix, 0.0f), (float)(W - 1));
    iy = fminf(fmaxf(iy, 0.0f), (float)(H - 1));

    float x0f = floorf(ix);
    float y0f = floorf(iy);
    wx[n] = ix - x0f;
    wy[n] = iy - y0f;

    int x0 = (int)x0f;
    int y0 = (int)y0f;

    // q = (c[y0][x0], c[y1][x0], c[y0][x0+1], c[y1][x0+1]) in one request.
    unsigned off = (unsigned)((y0 * WP + x0) * 8);
    asm volatile("global_load_dwordx4 %0, %1, %2"
                 : "=v"(q[n]) : "v"(off), "s"(Tb));
  }

  // ---- depth-channel loads (coalesced) — issued while gathers in flight ----
  const float* dptr = depth + (size_t)b * D * HW + hw;
  float vdep[D];
#pragma unroll
  for (int d = 0; d < D; ++d) vdep[d] = dptr[(size_t)d * HW];

  // Drain, then fence the scheduler (guide rule #18) so consumers can't be
  // hoisted above the wait.
  asm volatile("s_waitcnt vmcnt(0)" ::: "memory");
  __builtin_amdgcn_sched_barrier(0);

  // ---- bilinear combine + sort + write ----
  float v[NC];
#pragma unroll
  for (int d = 0; d < D; ++d) v[d] = vdep[d];
#pragma unroll
  for (int n = 0; n < NN; ++n) {
    float col0 = q[n].x * (1.0f - wy[n]) + q[n].y * wy[n];
    float col1 = q[n].z * (1.0f - wy[n]) + q[n].w * wy[n];
    v[D + n] = col0 * (1.0f - wx[n]) + col1 * wx[n];
  }

  sort17(v);

  float* optr = out + (size_t)b * NC * HW + hw;
#pragma unroll
  for (int c = 0; c < NC; ++c) {
    optr[(size_t)c * HW] = v[c];
  }
}

// ---------- fallback (R3-winning kernel) if ws_size is too small ----------
struct __attribute__((packed, aligned(4))) fpair { float a, b; };

__global__ __launch_bounds__(256) void prop_sort_fallback(
    const float* __restrict__ depth,
    const float* __restrict__ grid,
    float* __restrict__ out) {
  int idx = blockIdx.x * blockDim.x + threadIdx.x;
  if (idx >= B * HW) return;
  int b  = idx / HW;
  int hw = idx - b * HW;
  int h  = hw / W;
  int w  = hw - h * W;

  float v[NC];
  const float* dptr = depth + (size_t)b * D * HW + hw;
#pragma unroll
  for (int d = 0; d < D; ++d) v[d] = dptr[(size_t)d * HW];

  const float* center = depth + (size_t)b * D * HW + (size_t)(D / 2) * HW;
  const float2* gp = reinterpret_cast<const float2*>(grid)
                     + ((size_t)b * NN * H + h) * W + w;
#pragma unroll
  for (int n = 0; n < NN; ++n) {
    float2 g = gp[(size_t)n * HW];
    float ix = ((g.x + 1.0f) * (float)W - 1.0f) * 0.5f;
    float iy = ((g.y + 1.0f) * (float)H - 1.0f) * 0.5f;
    ix = fminf(fmaxf(ix, 0.0f), (float)(W - 1));
    iy = fminf(fmaxf(iy, 0.0f), (float)(H - 1));
    float x0f = floorf(ix), y0f = floorf(iy);
    float wx = ix - x0f, wy = iy - y0f;
    int x0 = (int)x0f, y0 = (int)y0f;
    int y1 = min(y0 + 1, H - 1);
    fpair p0 = *reinterpret_cast<const fpair*>(center + y0 * W + x0);
    fpair p1 = *reinterpret_cast<const fpair*>(center + y1 * W + x0);
    float vtop = p0.a * (1.0f - wx) + p0.b * wx;
    float vbot = p1.a * (1.0f - wx) + p1.b * wx;
    v[D + n] = vtop * (1.0f - wy) + vbot * wy;
  }

  sort17(v);
  float* optr = out + (size_t)b * NC * HW + hw;
#pragma unroll
  for (int c = 0; c < NC; ++c) optr[(size_t)c * HW] = v[c];
}

extern "C" void kernel_launch(void* const* d_in, const int* in_sizes, int n_in,
                              void* d_out, int out_size, void* d_ws, size_t ws_size,
                              hipStream_t stream) {
  const float* depth = (const float*)d_in[0];
  const float* grid  = (const float*)d_in[1];
  float* out = (float*)d_out;

  if (ws_size >= T_BYTES) {
    float2* T = (float2*)d_ws;
    int tblocks = (B * TPLANE + BLOCK - 1) / BLOCK;
    build_T_kernel<<<tblocks, BLOCK, 0, stream>>>(depth, T);
    prop_sort_T_kernel<<<B * BLOCKS_PER_B, BLOCK, 0, stream>>>(depth, grid, T, out);
  } else {
    int nblocks = (B * HW + BLOCK - 1) / BLOCK;
    prop_sort_fallback<<<nblocks, BLOCK, 0, stream>>>(depth, grid, out);
  }
}